// Round 1
// baseline (256.050 us; speedup 1.0000x reference)
//
#include <hip/hip_runtime.h>
#include <cstdint>
#include <cstddef>

#define EPSF 1e-6f

// ws layout (floats):
//   [0    ..  575] w1n branch0 (glob-normalized)   64*9
//   [576  .. 1151] w1n branch1 (row-normalized)    64*9
//   [1152 .. 9343] w2n branch0 (glob-normalized)  128*64
//   [9344 ..17535] w2n branch1 (row-normalized)   128*64

__global__ __launch_bounds__(256) void prep_weights(const float* __restrict__ w1,
                                                    const float* __restrict__ w2,
                                                    float* __restrict__ ws) {
    __shared__ float part1[4], part2[4];
    __shared__ float s1row[64];
    __shared__ float s2row[128];
    __shared__ float tot[2];

    const int t = threadIdx.x;
    const int ln = t & 63;
    const int wv = t >> 6;

    // global sums of squares
    float s1 = 0.f;
    for (int i = t; i < 64 * 9; i += 256) { float v = w1[i]; s1 += v * v; }
    float s2 = 0.f;
    for (int i = t; i < 128 * 64; i += 256) { float v = w2[i]; s2 += v * v; }
    #pragma unroll
    for (int d = 32; d > 0; d >>= 1) {
        s1 += __shfl_down(s1, d);
        s2 += __shfl_down(s2, d);
    }
    if (ln == 0) { part1[wv] = s1; part2[wv] = s2; }

    // row sums
    if (t < 64) {
        float rs = 0.f;
        #pragma unroll
        for (int k = 0; k < 9; ++k) { float v = w1[t * 9 + k]; rs += v * v; }
        s1row[t] = rs;
    } else if (t < 192) {
        const int o = t - 64;
        float rs = 0.f;
        for (int c = 0; c < 64; ++c) { float v = w2[o * 64 + c]; rs += v * v; }
        s2row[o] = rs;
    }
    __syncthreads();
    if (t == 0) tot[0] = part1[0] + part1[1] + part1[2] + part1[3];
    if (t == 1) tot[1] = part2[0] + part2[1] + part2[2] + part2[3];
    __syncthreads();

    const float t1 = tot[0];
    const float t2 = tot[1];
    for (int i = t; i < 64 * 9; i += 256) {
        float q = w1[i] * w1[i];
        ws[i] = q / t1;
        ws[576 + i] = q / s1row[i / 9];
    }
    for (int i = t; i < 128 * 64; i += 256) {
        float q = w2[i] * w2[i];
        ws[1152 + i] = q / t2;
        ws[1152 + 8192 + i] = q / s2row[i / 64];
    }
}

// grid: (62, 2, 32)  block: 256
// block = (out-row h, branch, batch b). lane = column. wave wv owns channels
// [wv*16, wv*16+16) in phase 1 and output channels [wv*32, wv*32+32) in phase 2.
__global__ __launch_bounds__(256) void conv_fused(const float* __restrict__ x,
                                                  const float* __restrict__ wn,
                                                  float* __restrict__ out) {
    const int h = blockIdx.x;       // 0..61
    const int branch = blockIdx.y;  // 0..1
    const int b = blockIdx.z;       // 0..31
    const int t = threadIdx.x;
    const int lane = t & 63;
    const int wv = __builtin_amdgcn_readfirstlane(t >> 6);  // force wave-uniform SGPR

    __shared__ float rot[64][64];   // [c][j]; bank = j%32 -> 2-way alias (free)

    const float* __restrict__ w1n = wn + branch * 576;
    const float* __restrict__ w2n = wn + 1152 + branch * 8192;
    const float* __restrict__ xb = x + (size_t)(b * 2 + branch) * (64 * 4096);

    // ---- phase 1: depthwise 3x3 for one output row, 16 channels per wave ----
    #pragma unroll 4
    for (int i = 0; i < 16; ++i) {
        const int c = wv * 16 + i;
        const float* xp = xb + c * 4096 + h * 64 + lane;
        float r0 = xp[0];
        float r1 = xp[64];
        float r2 = xp[128];
        if (branch) {   // block-uniform branch
            r0 = __logf(r0 + EPSF);
            r1 = __logf(r1 + EPSF);
            r2 = __logf(r2 + EPSF);
        }
        const float* wc = w1n + c * 9;   // wave-uniform -> s_load
        const float a1 = __shfl_down(r0, 1), a2 = __shfl_down(r0, 2);
        const float b1 = __shfl_down(r1, 1), b2 = __shfl_down(r1, 2);
        const float c1 = __shfl_down(r2, 1), c2 = __shfl_down(r2, 2);
        float s = r0 * wc[0] + a1 * wc[1] + a2 * wc[2]
                + r1 * wc[3] + b1 * wc[4] + b2 * wc[5]
                + r2 * wc[6] + c1 * wc[7] + c2 * wc[8];
        rot[c][lane] = s;
    }
    __syncthreads();

    // ---- phase 2: pointwise 64 -> 32 outs per wave, register-blocked ----
    float acc[32];
    #pragma unroll
    for (int oi = 0; oi < 32; ++oi) acc[oi] = 0.f;

    for (int cc = 0; cc < 64; cc += 8) {
        float r[8];
        #pragma unroll
        for (int e = 0; e < 8; ++e) r[e] = rot[cc + e][lane];
        const float* wp = w2n + (wv * 32) * 64 + cc;   // wave-uniform rows -> s_load
        #pragma unroll
        for (int oi = 0; oi < 32; ++oi) {
            const float* wrow = wp + oi * 64;
            #pragma unroll
            for (int e = 0; e < 8; ++e) acc[oi] += r[e] * wrow[e];
        }
    }

    // ---- store: coalesced 62-wide rows ----
    if (lane < 62) {
        const size_t base =
            ((size_t)((b * 2 + branch) * 128 + wv * 32)) * 3844 + (size_t)h * 62 + lane;
        #pragma unroll 4
        for (int oi = 0; oi < 32; ++oi) {
            float v = acc[oi];
            if (branch) v = __expf(v);
            out[base + (size_t)oi * 3844] = v;
        }
    }
}

extern "C" void kernel_launch(void* const* d_in, const int* in_sizes, int n_in,
                              void* d_out, int out_size, void* d_ws, size_t ws_size,
                              hipStream_t stream) {
    const float* x  = (const float*)d_in[0];
    const float* w1 = (const float*)d_in[1];
    const float* w2 = (const float*)d_in[2];
    float* out = (float*)d_out;
    float* ws  = (float*)d_ws;

    prep_weights<<<1, 256, 0, stream>>>(w1, w2, ws);

    dim3 grid(62, 2, 32);
    conv_fused<<<grid, 256, 0, stream>>>(x, ws, out);
}

// Round 2
// 238.559 us; speedup vs baseline: 1.0733x; 1.0733x over previous
//
#include <hip/hip_runtime.h>
#include <cstdint>
#include <cstddef>

#define EPSF 1e-6f

typedef __attribute__((ext_vector_type(4))) float f32x4;
typedef __attribute__((ext_vector_type(8))) short s16x8;

static __device__ __forceinline__ unsigned short f2bf(float f) {
    unsigned u = __float_as_uint(f);
    u += 0x7FFFu + ((u >> 16) & 1u);
    return (unsigned short)(u >> 16);
}
static __device__ __forceinline__ float bf2f(unsigned short h) {
    return __uint_as_float(((unsigned)h) << 16);
}
// fp32 -> (bf16 hi, bf16 lo) packed in one u32; v ~= hi + lo to ~17 bits
static __device__ __forceinline__ unsigned packHL(float v) {
    unsigned short h = f2bf(v);
    float r = v - bf2f(h);
    unsigned short l = f2bf(r);
    return ((unsigned)h << 16) | (unsigned)l;
}

// ws layout (4B units):
//   [0    ..  575] w1n branch0 (glob-normalized, fp32)
//   [576  .. 1151] w1n branch1 (row-normalized, fp32)
//   [1152 .. 9343] w2 branch0, bf16 hi/lo packed u32 [128][64]
//   [9344 ..17535] w2 branch1, bf16 hi/lo packed u32 [128][64]
__global__ __launch_bounds__(256) void prep_weights(const float* __restrict__ w1,
                                                    const float* __restrict__ w2,
                                                    float* __restrict__ ws) {
    __shared__ float part1[4], part2[4];
    __shared__ float s1row[64];
    __shared__ float s2row[128];
    __shared__ float tot[2];

    const int t = threadIdx.x;
    const int ln = t & 63;
    const int wv = t >> 6;

    float s1 = 0.f;
    for (int i = t; i < 64 * 9; i += 256) { float v = w1[i]; s1 += v * v; }
    float s2 = 0.f;
    const float4* w2v = (const float4*)w2;
    for (int i = t; i < 2048; i += 256) {
        float4 v = w2v[i];
        s2 += v.x * v.x + v.y * v.y + v.z * v.z + v.w * v.w;
    }
    #pragma unroll
    for (int d = 32; d > 0; d >>= 1) {
        s1 += __shfl_down(s1, d);
        s2 += __shfl_down(s2, d);
    }
    if (ln == 0) { part1[wv] = s1; part2[wv] = s2; }

    if (t < 64) {
        float rs = 0.f;
        #pragma unroll
        for (int k = 0; k < 9; ++k) { float v = w1[t * 9 + k]; rs += v * v; }
        s1row[t] = rs;
    } else if (t < 192) {
        const int o = t - 64;
        float rs = 0.f;
        const float4* p = (const float4*)(w2 + o * 64);
        #pragma unroll
        for (int k = 0; k < 16; ++k) {
            float4 v = p[k];
            rs += v.x * v.x + v.y * v.y + v.z * v.z + v.w * v.w;
        }
        s2row[o] = rs;
    }
    __syncthreads();
    if (t == 0) tot[0] = part1[0] + part1[1] + part1[2] + part1[3];
    if (t == 1) tot[1] = part2[0] + part2[1] + part2[2] + part2[3];
    __syncthreads();

    const float t1 = tot[0];
    const float t2 = tot[1];
    for (int i = t; i < 64 * 9; i += 256) {
        float q = w1[i] * w1[i];
        ws[i] = q / t1;
        ws[576 + i] = q / s1row[i / 9];
    }
    unsigned* wsu = (unsigned*)ws;
    for (int i = t; i < 8192; i += 256) {
        float q = w2[i] * w2[i];
        wsu[1152 + i]        = packHL(q / t2);
        wsu[1152 + 8192 + i] = packHL(q / s2row[i >> 6]);
    }
}

// grid: (62, 2, 32)  block: 256
// phase 1: wave wv computes depthwise 3x3 (+log) for channels [wv*16,wv*16+16),
//          lane = column; result packed bf16 hi/lo into LDS rotT[px][c], stride 65.
// phase 2: wave wv computes out-channels [wv*32,wv*32+32) x 64 px via
//          mfma_f32_16x16x32_bf16 with 3-term hi/lo split (AhBh+AhBl+AlBh).
__global__ __launch_bounds__(256) void conv_fused(const float* __restrict__ x,
                                                  const float* __restrict__ ws,
                                                  float* __restrict__ out) {
    const int h = blockIdx.x;       // 0..61
    const int branch = blockIdx.y;  // 0..1
    const int b = blockIdx.z;       // 0..31
    const int t = threadIdx.x;
    const int lane = t & 63;
    const int wv = __builtin_amdgcn_readfirstlane(t >> 6);
    const int lm = lane & 15;
    const int quad = lane >> 4;

    __shared__ unsigned rotT[64 * 65];  // [px][c], stride 65 dwords -> bank (px+c)%32

    const float* __restrict__ w1n = ws + branch * 576;
    const unsigned* __restrict__ w2p = (const unsigned*)ws + 1152 + branch * 8192;
    const float* __restrict__ xb = x + (size_t)(b * 2 + branch) * (64 * 4096);

    // ---- phase 1: depthwise 3x3 for one output row ----
    #pragma unroll 4
    for (int i = 0; i < 16; ++i) {
        const int c = wv * 16 + i;
        const float* xp = xb + c * 4096 + h * 64 + lane;
        float r0 = xp[0];
        float r1 = xp[64];
        float r2 = xp[128];
        if (branch) {
            r0 = __logf(r0 + EPSF);
            r1 = __logf(r1 + EPSF);
            r2 = __logf(r2 + EPSF);
        }
        const float* wc = w1n + c * 9;  // wave-uniform -> s_load
        const float a1 = __shfl_down(r0, 1), a2 = __shfl_down(r0, 2);
        const float b1 = __shfl_down(r1, 1), b2 = __shfl_down(r1, 2);
        const float c1 = __shfl_down(r2, 1), c2 = __shfl_down(r2, 2);
        float s = r0 * wc[0] + a1 * wc[1] + a2 * wc[2]
                + r1 * wc[3] + b1 * wc[4] + b2 * wc[5]
                + r2 * wc[6] + c1 * wc[7] + c2 * wc[8];
        rotT[lane * 65 + c] = packHL(s);
    }
    __syncthreads();

    // ---- phase 2: MFMA GEMM out[128][64px] = w2[128][64] * rot[64][64px] ----
    // A fragments: A[m=lane&15][k=quad*8+j], contiguous u32 loads from w2p.
    s16x8 aH[2][2], aL[2][2];
    #pragma unroll
    for (int mt = 0; mt < 2; ++mt) {
        #pragma unroll
        for (int kk = 0; kk < 2; ++kk) {
            const unsigned* p = w2p + (wv * 32 + mt * 16 + lm) * 64 + kk * 32 + quad * 8;
            #pragma unroll
            for (int j = 0; j < 8; ++j) {
                unsigned u = p[j];
                aH[mt][kk][j] = (short)(u >> 16);
                aL[mt][kk][j] = (short)(u & 0xffffu);
            }
        }
    }

    f32x4 acc[2][4];
    #pragma unroll
    for (int mt = 0; mt < 2; ++mt)
        #pragma unroll
        for (int nt = 0; nt < 4; ++nt)
            acc[mt][nt] = (f32x4){0.f, 0.f, 0.f, 0.f};

    #pragma unroll
    for (int nt = 0; nt < 4; ++nt) {
        #pragma unroll
        for (int kk = 0; kk < 2; ++kk) {
            // B fragment: B[k=quad*8+j][n=lane&15] = rot[c][px] = rotT[px][c]
            const unsigned* lp = &rotT[(nt * 16 + lm) * 65 + kk * 32 + quad * 8];
            s16x8 bH, bL;
            #pragma unroll
            for (int j = 0; j < 8; ++j) {
                unsigned u = lp[j];
                bH[j] = (short)(u >> 16);
                bL[j] = (short)(u & 0xffffu);
            }
            #pragma unroll
            for (int mt = 0; mt < 2; ++mt) {
                acc[mt][nt] = __builtin_amdgcn_mfma_f32_16x16x32_bf16(aH[mt][kk], bH, acc[mt][nt], 0, 0, 0);
                acc[mt][nt] = __builtin_amdgcn_mfma_f32_16x16x32_bf16(aH[mt][kk], bL, acc[mt][nt], 0, 0, 0);
                acc[mt][nt] = __builtin_amdgcn_mfma_f32_16x16x32_bf16(aL[mt][kk], bH, acc[mt][nt], 0, 0, 0);
            }
        }
    }

    // ---- epilogue: D row = oc (quad*4+reg), col = px (lane&15) ----
    #pragma unroll
    for (int mt = 0; mt < 2; ++mt) {
        const int oc0 = wv * 32 + mt * 16 + quad * 4;
        #pragma unroll
        for (int nt = 0; nt < 4; ++nt) {
            const int px = nt * 16 + lm;
            if (px < 62) {
                const size_t base =
                    ((size_t)((b * 2 + branch) * 128 + oc0)) * 3844 + (size_t)h * 62 + px;
                #pragma unroll
                for (int r = 0; r < 4; ++r) {
                    float v = acc[mt][nt][r];
                    if (branch) v = __expf(v);
                    out[base + (size_t)r * 3844] = v;
                }
            }
        }
    }
}

extern "C" void kernel_launch(void* const* d_in, const int* in_sizes, int n_in,
                              void* d_out, int out_size, void* d_ws, size_t ws_size,
                              hipStream_t stream) {
    const float* x  = (const float*)d_in[0];
    const float* w1 = (const float*)d_in[1];
    const float* w2 = (const float*)d_in[2];
    float* out = (float*)d_out;
    float* ws  = (float*)d_ws;

    prep_weights<<<1, 256, 0, stream>>>(w1, w2, ws);

    dim3 grid(62, 2, 32);
    conv_fused<<<grid, 256, 0, stream>>>(x, ws, out);
}

// Round 3
// 219.120 us; speedup vs baseline: 1.1685x; 1.0887x over previous
//
#include <hip/hip_runtime.h>
#include <cstdint>
#include <cstddef>

#define EPSF 1e-6f

typedef __attribute__((ext_vector_type(4))) float f32x4;
typedef __attribute__((ext_vector_type(8))) short s16x8;
typedef union { s16x8 v; unsigned u[4]; } s16x8u;

static __device__ __forceinline__ unsigned short f2bf(float f) {
    unsigned u = __float_as_uint(f);
    u += 0x7FFFu + ((u >> 16) & 1u);
    return (unsigned short)(u >> 16);
}
static __device__ __forceinline__ float bf2f(unsigned short h) {
    return __uint_as_float(((unsigned)h) << 16);
}
// fp32 -> (bf16 hi, bf16 lo) packed in one u32; v ~= hi + lo to ~17 bits
static __device__ __forceinline__ unsigned packHL(float v) {
    unsigned short h = f2bf(v);
    float r = v - bf2f(h);
    unsigned short l = f2bf(r);
    return ((unsigned)h << 16) | (unsigned)l;
}

// ws layout (4B units):
//   [0    ..  575] w1t branch0: [wv][chsub][cg][k] transposed normalized taps
//   [576  .. 1151] w1t branch1
//   [1152 .. 9343] w2 branch0, bf16 hi/lo packed u32 [128][64]
//   [9344 ..17535] w2 branch1, bf16 hi/lo packed u32 [128][64]
__global__ __launch_bounds__(256) void prep_weights(const float* __restrict__ w1,
                                                    const float* __restrict__ w2,
                                                    float* __restrict__ ws) {
    __shared__ float part1[4], part2[4];
    __shared__ float s1row[64];
    __shared__ float s2row[128];
    __shared__ float tot[2];

    const int t = threadIdx.x;
    const int ln = t & 63;
    const int wv = t >> 6;

    float s1 = 0.f;
    for (int i = t; i < 64 * 9; i += 256) { float v = w1[i]; s1 += v * v; }
    float s2 = 0.f;
    const float4* w2v = (const float4*)w2;
    for (int i = t; i < 2048; i += 256) {
        float4 v = w2v[i];
        s2 += v.x * v.x + v.y * v.y + v.z * v.z + v.w * v.w;
    }
    #pragma unroll
    for (int d = 32; d > 0; d >>= 1) {
        s1 += __shfl_down(s1, d);
        s2 += __shfl_down(s2, d);
    }
    if (ln == 0) { part1[wv] = s1; part2[wv] = s2; }

    if (t < 64) {
        float rs = 0.f;
        #pragma unroll
        for (int k = 0; k < 9; ++k) { float v = w1[t * 9 + k]; rs += v * v; }
        s1row[t] = rs;
    } else if (t < 192) {
        const int o = t - 64;
        float rs = 0.f;
        const float4* p = (const float4*)(w2 + o * 64);
        #pragma unroll
        for (int k = 0; k < 16; ++k) {
            float4 v = p[k];
            rs += v.x * v.x + v.y * v.y + v.z * v.z + v.w * v.w;
        }
        s2row[o] = rs;
    }
    __syncthreads();
    if (t == 0) tot[0] = part1[0] + part1[1] + part1[2] + part1[3];
    if (t == 1) tot[1] = part2[0] + part2[1] + part2[2] + part2[3];
    __syncthreads();

    const float t1 = tot[0];
    const float t2 = tot[1];
    for (int i = t; i < 64 * 9; i += 256) {
        const int c = i / 9;
        const int k = i - c * 9;
        const int idx = (c >> 4) * 144 + (c & 3) * 36 + ((c >> 2) & 3) * 9 + k;
        float q = w1[i] * w1[i];
        ws[idx] = q / t1;
        ws[576 + idx] = q / s1row[c];
    }
    unsigned* wsu = (unsigned*)ws;
    for (int i = t; i < 8192; i += 256) {
        float q = w2[i] * w2[i];
        wsu[1152 + i]        = packHL(q / t2);
        wsu[1152 + 8192 + i] = packHL(q / s2row[i >> 6]);
    }
}

// grid: (62, 2, 32)  block: 256
// phase 1: lane = (chsub = lane>>4 -> channel-in-group, c4 = lane&15 -> 4-col
//          group). float4 loads, 2 shfls/row for cross-lane cols, 36 FMA taps,
//          packed bf16 hi/lo into LDS rotT[px][c] (stride 65 -> 2-way banks).
// phase 2: wave wv computes out-channels [wv*32,wv*32+32) x 64 px via
//          mfma_f32_16x16x32_bf16 with 3-term hi/lo split (AhBh+AhBl+AlBh).
__global__ __launch_bounds__(256) void conv_fused(const float* __restrict__ x,
                                                  const float* __restrict__ ws,
                                                  float* __restrict__ out) {
    const int h = blockIdx.x;       // 0..61
    const int branch = blockIdx.y;  // 0..1
    const int b = blockIdx.z;       // 0..31
    const int t = threadIdx.x;
    const int lane = t & 63;
    const int wv = __builtin_amdgcn_readfirstlane(t >> 6);
    const int lm = lane & 15;
    const int quad = lane >> 4;
    const int c4 = lm;              // phase-1 column group
    const int chsub = quad;         // phase-1 channel-in-group

    __shared__ unsigned rotT[64 * 65];  // [px][c], stride 65 dwords

    const float* __restrict__ w1t = ws + branch * 576;
    const unsigned* __restrict__ w2p = (const unsigned*)ws + 1152 + branch * 8192;
    const float* __restrict__ xb = x + (size_t)(b * 2 + branch) * (64 * 4096);

    // ---- phase 1: depthwise 3x3 for one output row, float4-vectorized ----
    const float* xrow = xb + h * 64 + 4 * c4;
    #pragma unroll 2
    for (int cg = 0; cg < 4; ++cg) {
        const int c = wv * 16 + cg * 4 + chsub;
        const float* xp = xrow + c * 4096;
        float4 v0 = *(const float4*)xp;
        float4 v1 = *(const float4*)(xp + 64);
        float4 v2 = *(const float4*)(xp + 128);
        if (branch) {
            v0.x = __logf(v0.x + EPSF); v0.y = __logf(v0.y + EPSF);
            v0.z = __logf(v0.z + EPSF); v0.w = __logf(v0.w + EPSF);
            v1.x = __logf(v1.x + EPSF); v1.y = __logf(v1.y + EPSF);
            v1.z = __logf(v1.z + EPSF); v1.w = __logf(v1.w + EPSF);
            v2.x = __logf(v2.x + EPSF); v2.y = __logf(v2.y + EPSF);
            v2.z = __logf(v2.z + EPSF); v2.w = __logf(v2.w + EPSF);
        }
        const float sx0 = __shfl_down(v0.x, 1), sy0 = __shfl_down(v0.y, 1);
        const float sx1 = __shfl_down(v1.x, 1), sy1 = __shfl_down(v1.y, 1);
        const float sx2 = __shfl_down(v2.x, 1), sy2 = __shfl_down(v2.y, 1);
        const float* wc = w1t + wv * 144 + chsub * 36 + cg * 9;  // L1-hot
        const float w0 = wc[0], w1_ = wc[1], w2_ = wc[2];
        const float w3 = wc[3], w4 = wc[4], w5 = wc[5];
        const float w6 = wc[6], w7 = wc[7], w8 = wc[8];
        // px = 4*c4 + i uses cols (px, px+1, px+2); px 62/63 garbage, discarded
        float p0 = v0.x * w0 + v0.y * w1_ + v0.z * w2_
                 + v1.x * w3 + v1.y * w4  + v1.z * w5
                 + v2.x * w6 + v2.y * w7  + v2.z * w8;
        float p1 = v0.y * w0 + v0.z * w1_ + v0.w * w2_
                 + v1.y * w3 + v1.z * w4  + v1.w * w5
                 + v2.y * w6 + v2.z * w7  + v2.w * w8;
        float p2 = v0.z * w0 + v0.w * w1_ + sx0 * w2_
                 + v1.z * w3 + v1.w * w4  + sx1 * w5
                 + v2.z * w6 + v2.w * w7  + sx2 * w8;
        float p3 = v0.w * w0 + sx0 * w1_ + sy0 * w2_
                 + v1.w * w3 + sx1 * w4  + sy1 * w5
                 + v2.w * w6 + sx2 * w7  + sy2 * w8;
        unsigned* rp = &rotT[(4 * c4) * 65 + c];
        rp[0]   = packHL(p0);
        rp[65]  = packHL(p1);
        rp[130] = packHL(p2);
        rp[195] = packHL(p3);
    }

    // ---- A-fragment raw loads (L2-hot) — latency hides under barrier wait ----
    unsigned araw[2][2][8];
    #pragma unroll
    for (int mt = 0; mt < 2; ++mt) {
        #pragma unroll
        for (int kk = 0; kk < 2; ++kk) {
            const unsigned* p = w2p + (wv * 32 + mt * 16 + lm) * 64 + kk * 32 + quad * 8;
            #pragma unroll
            for (int j = 0; j < 8; ++j) araw[mt][kk][j] = p[j];
        }
    }
    __syncthreads();

    // unpack A into bf16 hi/lo fragments via v_perm
    s16x8u aH[2][2], aL[2][2];
    #pragma unroll
    for (int mt = 0; mt < 2; ++mt)
        #pragma unroll
        for (int kk = 0; kk < 2; ++kk)
            #pragma unroll
            for (int j2 = 0; j2 < 4; ++j2) {
                unsigned u0 = araw[mt][kk][2 * j2], u1 = araw[mt][kk][2 * j2 + 1];
                aH[mt][kk].u[j2] = __builtin_amdgcn_perm(u1, u0, 0x07060302u);
                aL[mt][kk].u[j2] = __builtin_amdgcn_perm(u1, u0, 0x05040100u);
            }

    f32x4 acc[2][4];
    #pragma unroll
    for (int mt = 0; mt < 2; ++mt)
        #pragma unroll
        for (int nt = 0; nt < 4; ++nt)
            acc[mt][nt] = (f32x4){0.f, 0.f, 0.f, 0.f};

    #pragma unroll
    for (int nt = 0; nt < 4; ++nt) {
        #pragma unroll
        for (int kk = 0; kk < 2; ++kk) {
            // B fragment: B[k=quad*8+j][n=lane&15] = rot[c][px] = rotT[px][c]
            const unsigned* lp = &rotT[(nt * 16 + lm) * 65 + kk * 32 + quad * 8];
            s16x8u bH, bL;
            #pragma unroll
            for (int j2 = 0; j2 < 4; ++j2) {
                unsigned u0 = lp[2 * j2], u1 = lp[2 * j2 + 1];
                bH.u[j2] = __builtin_amdgcn_perm(u1, u0, 0x07060302u);
                bL.u[j2] = __builtin_amdgcn_perm(u1, u0, 0x05040100u);
            }
            #pragma unroll
            for (int mt = 0; mt < 2; ++mt) {
                acc[mt][nt] = __builtin_amdgcn_mfma_f32_16x16x32_bf16(aH[mt][kk].v, bH.v, acc[mt][nt], 0, 0, 0);
                acc[mt][nt] = __builtin_amdgcn_mfma_f32_16x16x32_bf16(aH[mt][kk].v, bL.v, acc[mt][nt], 0, 0, 0);
                acc[mt][nt] = __builtin_amdgcn_mfma_f32_16x16x32_bf16(aL[mt][kk].v, bH.v, acc[mt][nt], 0, 0, 0);
            }
        }
    }

    // ---- epilogue: D row = oc (quad*4+reg), col = px (lane&15) ----
    #pragma unroll
    for (int mt = 0; mt < 2; ++mt) {
        const int oc0 = wv * 32 + mt * 16 + quad * 4;
        #pragma unroll
        for (int nt = 0; nt < 4; ++nt) {
            const int px = nt * 16 + lm;
            if (px < 62) {
                const size_t base =
                    ((size_t)((b * 2 + branch) * 128 + oc0)) * 3844 + (size_t)h * 62 + px;
                #pragma unroll
                for (int r = 0; r < 4; ++r) {
                    float v = acc[mt][nt][r];
                    if (branch) v = __expf(v);
                    out[base + (size_t)r * 3844] = v;
                }
            }
        }
    }
}

extern "C" void kernel_launch(void* const* d_in, const int* in_sizes, int n_in,
                              void* d_out, int out_size, void* d_ws, size_t ws_size,
                              hipStream_t stream) {
    const float* x  = (const float*)d_in[0];
    const float* w1 = (const float*)d_in[1];
    const float* w2 = (const float*)d_in[2];
    float* out = (float*)d_out;
    float* ws  = (float*)d_ws;

    prep_weights<<<1, 256, 0, stream>>>(w1, w2, ws);

    dim3 grid(62, 2, 32);
    conv_fused<<<grid, 256, 0, stream>>>(x, ws, out);
}